// Round 9
// baseline (9715.145 us; speedup 1.0000x reference)
//
#include <hip/hip_runtime.h>
#include <hip/hip_bf16.h>

#define M_TOTAL 131072
#define ATT_SCALE 0.17677669529663687f
#define LN_EPS 1e-5f
#define CDIV(a,b) (((a)+(b)-1)/(b))

using bf16x8 = __attribute__((ext_vector_type(8))) short;
using f32x4  = __attribute__((ext_vector_type(4))) float;

__device__ __forceinline__ float wredsum(float v){
#pragma unroll
  for (int m = 32; m; m >>= 1) v += __shfl_xor(v, m, 64);
  return v;
}

// fp32 -> bf16 (round-to-nearest-even) as raw bits
__device__ __forceinline__ unsigned short f2b(float x){
  union { float f; unsigned u; } v; v.f = x;
  unsigned r = v.u + 0x7FFFu + ((v.u >> 16) & 1u);
  return (unsigned short)(r >> 16);
}
__device__ __forceinline__ float b2f(unsigned short u){
  union { unsigned u32; float f; } v; v.u32 = (unsigned)u << 16; return v.f;
}

__global__ void zero1(float* p){ if (threadIdx.x == 0) *p = 0.f; }

// ---- one-time weight conversion: fp32 [K][N] -> bf16 transposed [N][K] ----
__global__ void convert_qkv(const float* __restrict__ Wk, const float* __restrict__ Wq,
                            const float* __restrict__ Wv, unsigned short* __restrict__ WrT){
  int idx = blockIdx.x * 256 + threadIdx.x;
  if (idx >= 8 * 768 * 256) return;
  int k = idx & 255;
  int n = (idx >> 8) % 768;
  int i = idx / (768 * 256);
  int sel = n >> 8, nn = n & 255, hh = nn >> 6, d = nn & 63;
  const float* W = sel == 0 ? Wk : sel == 1 ? Wq : Wv;
  WrT[idx] = f2b(W[((size_t)(i * 4 + hh) * 256 + k) * 64 + d]);
}

__global__ void convert_t(const float* __restrict__ in, unsigned short* __restrict__ outp,
                          int N, int K, int total){
  int idx = blockIdx.x * 256 + threadIdx.x;
  if (idx >= total) return;
  int k = idx % K;
  int n = (idx / K) % N;
  int i = idx / (K * N);
  outp[idx] = f2b(in[((size_t)i * K + k) * N + n]);
}

// ---- MFMA bf16 GEMM: C[r][n] = A[r][:] @ B[:][n] + bias[n] ----
// A bf16 [M][K]; BT bf16 transposed [N][K]. 128x128 tile, BK=64, 4 waves (2x2).
template<bool RELU, bool BF16OUT>
__global__ __launch_bounds__(256)
void gemm_bf(const unsigned short* __restrict__ A, const unsigned short* __restrict__ BT,
             const float* __restrict__ bias, float* __restrict__ Cf,
             unsigned short* __restrict__ Cb, int N, int K){
  __shared__ unsigned short As[128][72];
  __shared__ unsigned short Bs[128][72];
  const int tid = threadIdx.x;
  const int rowBase = blockIdx.y * 128, colBase = blockIdx.x * 128;
  const int w = tid >> 6, lane = tid & 63;
  const int wm = w >> 1, wn = w & 1;
  const int lm = lane & 15, lk = lane >> 4;
  const int srow = tid >> 3, scol = (tid & 7) * 8;

  f32x4 acc[4][4];
#pragma unroll
  for (int m = 0; m < 4; ++m)
#pragma unroll
    for (int n = 0; n < 4; ++n) acc[m][n] = (f32x4){0.f, 0.f, 0.f, 0.f};

  for (int kt = 0; kt < K; kt += 64){
#pragma unroll
    for (int q = 0; q < 4; ++q){
      int r = srow + 32 * q;
      *(uint4*)&As[r][scol] = *(const uint4*)(A  + (size_t)(rowBase + r) * K + kt + scol);
      *(uint4*)&Bs[r][scol] = *(const uint4*)(BT + (size_t)(colBase + r) * K + kt + scol);
    }
    __syncthreads();
#pragma unroll
    for (int half = 0; half < 2; ++half){
      bf16x8 a[4], b[4];
#pragma unroll
      for (int m = 0; m < 4; ++m)
        a[m] = *(const bf16x8*)&As[wm * 64 + m * 16 + lm][half * 32 + lk * 8];
#pragma unroll
      for (int n = 0; n < 4; ++n)
        b[n] = *(const bf16x8*)&Bs[wn * 64 + n * 16 + lm][half * 32 + lk * 8];
#pragma unroll
      for (int m = 0; m < 4; ++m)
#pragma unroll
        for (int n = 0; n < 4; ++n)
          acc[m][n] = __builtin_amdgcn_mfma_f32_16x16x32_bf16(a[m], b[n], acc[m][n], 0, 0, 0);
    }
    __syncthreads();
  }

#pragma unroll
  for (int m = 0; m < 4; ++m){
#pragma unroll
    for (int n = 0; n < 4; ++n){
      int c = colBase + wn * 64 + n * 16 + lm;
      float bv = bias ? bias[c] : 0.f;
#pragma unroll
      for (int i = 0; i < 4; ++i){
        int r = rowBase + wm * 64 + m * 16 + lk * 4 + i;
        float v = acc[m][n][i] + bv;
        if (RELU) v = fmaxf(v, 0.f);
        if (BF16OUT) Cb[(size_t)r * N + c] = f2b(v);
        else         Cf[(size_t)r * N + c] = v;
      }
    }
  }
}

// ---- fused GEMM (N=256) + bias + residual + LayerNorm ----
// C = A @ BT^T + bias; x = h + C; h = LN(x)*g + b; h_bf = bf16(h).
// 128x256 tile per block, 512 threads = 8 waves (2 wm x 4 wn). BK=64.
__global__ __launch_bounds__(512)
void gemm_ln(const unsigned short* __restrict__ A, const unsigned short* __restrict__ BT,
             const float* __restrict__ bias, float* __restrict__ h,
             unsigned short* __restrict__ h_bf,
             const float* __restrict__ g, const float* __restrict__ b, int K){
  __shared__ unsigned short As[128][72];
  __shared__ unsigned short Bs[256][72];
  __shared__ float redA[4][128];
  __shared__ float redB[4][128];
  const int tid = threadIdx.x;
  const int rowBase = blockIdx.x * 128;
  const int w = tid >> 6, lane = tid & 63;
  const int wm = w >> 2, wn = w & 3;
  const int lm = lane & 15, lk = lane >> 4;
  const int srow = tid >> 3, scol = (tid & 7) * 8;

  f32x4 acc[4][4];
#pragma unroll
  for (int m = 0; m < 4; ++m)
#pragma unroll
    for (int n = 0; n < 4; ++n) acc[m][n] = (f32x4){0.f, 0.f, 0.f, 0.f};

  for (int kt = 0; kt < K; kt += 64){
#pragma unroll
    for (int q = 0; q < 2; ++q){
      int r = srow + 64 * q;
      *(uint4*)&As[r][scol] = *(const uint4*)(A + (size_t)(rowBase + r) * K + kt + scol);
    }
#pragma unroll
    for (int q = 0; q < 4; ++q){
      int r = srow + 64 * q;
      *(uint4*)&Bs[r][scol] = *(const uint4*)(BT + (size_t)r * K + kt + scol);
    }
    __syncthreads();
#pragma unroll
    for (int half = 0; half < 2; ++half){
      bf16x8 a[4], b8[4];
#pragma unroll
      for (int m = 0; m < 4; ++m)
        a[m] = *(const bf16x8*)&As[wm * 64 + m * 16 + lm][half * 32 + lk * 8];
#pragma unroll
      for (int n = 0; n < 4; ++n)
        b8[n] = *(const bf16x8*)&Bs[wn * 64 + n * 16 + lm][half * 32 + lk * 8];
#pragma unroll
      for (int m = 0; m < 4; ++m)
#pragma unroll
        for (int n = 0; n < 4; ++n)
          acc[m][n] = __builtin_amdgcn_mfma_f32_16x16x32_bf16(a[m], b8[n], acc[m][n], 0, 0, 0);
    }
    __syncthreads();
  }

  // x = acc + bias + h (residual), in place
  float gg[4], bb[4], bv[4];
#pragma unroll
  for (int n = 0; n < 4; ++n){
    int c = wn * 64 + n * 16 + lm;
    bv[n] = bias[c]; gg[n] = g[c]; bb[n] = b[c];
  }
#pragma unroll
  for (int m = 0; m < 4; ++m)
#pragma unroll
    for (int i = 0; i < 4; ++i){
      size_t rr = (size_t)(rowBase + wm * 64 + m * 16 + lk * 4 + i) * 256;
#pragma unroll
      for (int n = 0; n < 4; ++n)
        acc[m][n][i] += bv[n] + h[rr + wn * 64 + n * 16 + lm];
    }

  // mean: per-thread 4-col partials -> 16-lane tree -> cross-wave LDS
  float pr[4][4];
#pragma unroll
  for (int m = 0; m < 4; ++m)
#pragma unroll
    for (int i = 0; i < 4; ++i)
      pr[m][i] = acc[m][0][i] + acc[m][1][i] + acc[m][2][i] + acc[m][3][i];
#pragma unroll
  for (int mask = 1; mask < 16; mask <<= 1)
#pragma unroll
    for (int m = 0; m < 4; ++m)
#pragma unroll
      for (int i = 0; i < 4; ++i)
        pr[m][i] += __shfl_xor(pr[m][i], mask, 64);
  if (lm == 0){
#pragma unroll
    for (int m = 0; m < 4; ++m)
#pragma unroll
      for (int i = 0; i < 4; ++i)
        redA[wn][wm * 64 + m * 16 + lk * 4 + i] = pr[m][i];
  }
  __syncthreads();
  float mean[4][4];
#pragma unroll
  for (int m = 0; m < 4; ++m)
#pragma unroll
    for (int i = 0; i < 4; ++i){
      int lr = wm * 64 + m * 16 + lk * 4 + i;
      mean[m][i] = (redA[0][lr] + redA[1][lr] + redA[2][lr] + redA[3][lr]) * (1.f / 256.f);
    }

  // variance
#pragma unroll
  for (int m = 0; m < 4; ++m)
#pragma unroll
    for (int i = 0; i < 4; ++i){
      float q = 0.f;
#pragma unroll
      for (int n = 0; n < 4; ++n){
        float d = acc[m][n][i] - mean[m][i];
        q += d * d;
      }
      pr[m][i] = q;
    }
#pragma unroll
  for (int mask = 1; mask < 16; mask <<= 1)
#pragma unroll
    for (int m = 0; m < 4; ++m)
#pragma unroll
      for (int i = 0; i < 4; ++i)
        pr[m][i] += __shfl_xor(pr[m][i], mask, 64);
  if (lm == 0){
#pragma unroll
    for (int m = 0; m < 4; ++m)
#pragma unroll
      for (int i = 0; i < 4; ++i)
        redB[wn][wm * 64 + m * 16 + lk * 4 + i] = pr[m][i];
  }
  __syncthreads();

#pragma unroll
  for (int m = 0; m < 4; ++m)
#pragma unroll
    for (int i = 0; i < 4; ++i){
      int lr = wm * 64 + m * 16 + lk * 4 + i;
      float var = (redB[0][lr] + redB[1][lr] + redB[2][lr] + redB[3][lr]) * (1.f / 256.f);
      float rstd = rsqrtf(var + LN_EPS);
      size_t rr = (size_t)(rowBase + lr) * 256;
#pragma unroll
      for (int n = 0; n < 4; ++n){
        int c = wn * 64 + n * 16 + lm;
        float nv = (acc[m][n][i] - mean[m][i]) * rstd * gg[n] + bb[n];
        h[rr + c] = nv;
        h_bf[rr + c] = f2b(nv);
      }
    }
}

// h[r][c] = tok[x[m]][c] + pos[x[m]][c] (pos indexed by TOKEN ids -- source bug preserved)
__global__ void embed_kernel(const int* __restrict__ x, const float* __restrict__ tok,
                             const float* __restrict__ pos, float* __restrict__ h,
                             unsigned short* __restrict__ h_bf, int row0, int nrows){
  int total = nrows * 256;
  for (int idx = blockIdx.x * blockDim.x + threadIdx.x; idx < total; idx += gridDim.x * blockDim.x){
    int r = idx >> 8, c = idx & 255;
    int t = x[row0 + r];
    float v = tok[t * 256 + c] + pos[t * 256 + c];
    h[idx] = v;
    h_bf[idx] = f2b(v);
  }
}

// ---- fused attention: one block per (seq, head), 128 threads; kqv in bf16 ----
__global__ __launch_bounds__(128)
void attn_fused(const unsigned short* __restrict__ kqv, unsigned short* __restrict__ attn){
  __shared__ float Kf[32][68];
  __shared__ float Qt[64][33];
  __shared__ float Vf[32][68];
  __shared__ float Ws[32][33];
  const int ls = blockIdx.x, hh = blockIdx.y;
  const int tid = threadIdx.x;

  for (int idx = tid; idx < 512; idx += 128){
    int t = idx >> 4, d4 = idx & 15;
    size_t base = (size_t)(ls * 32 + t) * 768 + hh * 64 + d4 * 4;
    ushort4 k4 = *(const ushort4*)(kqv + base);
    ushort4 q4 = *(const ushort4*)(kqv + base + 256);
    ushort4 v4 = *(const ushort4*)(kqv + base + 512);
    int d = d4 * 4;
    Kf[t][d+0] = b2f(k4.x); Kf[t][d+1] = b2f(k4.y); Kf[t][d+2] = b2f(k4.z); Kf[t][d+3] = b2f(k4.w);
    Qt[d+0][t] = b2f(q4.x); Qt[d+1][t] = b2f(q4.y); Qt[d+2][t] = b2f(q4.z); Qt[d+3][t] = b2f(q4.w);
    Vf[t][d+0] = b2f(v4.x); Vf[t][d+1] = b2f(v4.y); Vf[t][d+2] = b2f(v4.z); Vf[t][d+3] = b2f(v4.w);
  }
  __syncthreads();

  for (int idx = tid; idx < 1024; idx += 128){
    int s = idx & 31, t = idx >> 5;
    if (s <= t){
      float acc = 0.f;
#pragma unroll 16
      for (int d = 0; d < 64; ++d) acc = fmaf(Kf[t][d], Qt[d][s], acc);
      Ws[t][s] = acc * ATT_SCALE;
    }
  }
  __syncthreads();

  if (tid < 32){
    int t = tid;
    float mx = -1e30f;
    for (int s = 0; s <= t; ++s) mx = fmaxf(mx, Ws[t][s]);
    float sm = 0.f;
    for (int s = 0; s <= t; ++s){ float e = expf(Ws[t][s] - mx); Ws[t][s] = e; sm += e; }
    float inv = 1.f / sm;
    for (int s = 0; s <= t; ++s) Ws[t][s] *= inv;
    for (int s = t + 1; s < 32; ++s) Ws[t][s] = 0.f;
  }
  __syncthreads();

  for (int o = tid; o < 512; o += 128){
    int t = o >> 4, d4 = o & 15;
    float4 a4 = {0.f, 0.f, 0.f, 0.f};
#pragma unroll
    for (int s = 0; s < 32; ++s){
      float w = Ws[t][s];
      float4 v = *(const float4*)&Vf[s][d4 * 4];
      a4.x = fmaf(w, v.x, a4.x); a4.y = fmaf(w, v.y, a4.y);
      a4.z = fmaf(w, v.z, a4.z); a4.w = fmaf(w, v.w, a4.w);
    }
    ushort4 o4;
    o4.x = f2b(a4.x); o4.y = f2b(a4.y); o4.z = f2b(a4.z); o4.w = f2b(a4.w);
    *(ushort4*)(attn + (size_t)(ls * 32 + t) * 256 + hh * 64 + d4 * 4) = o4;
  }
}

// logits: fp32 store to out + lf scratch for loss. One thread per (r,v).
__global__ __launch_bounds__(256)
void logits_kernel(const float* __restrict__ h, const float* __restrict__ lmW,
                   const float* __restrict__ lmb, float* __restrict__ lf,
                   float* __restrict__ out, int nrows, int row0){
  long idx = (long)blockIdx.x * 256 + threadIdx.x;
  if (idx >= (long)nrows * 65) return;
  int v = (int)(idx % 65);
  int r = (int)(idx / 65);
  const float* hr = h + (size_t)r * 256;
  float acc = lmb[v];
  for (int c = 0; c < 256; ++c) acc = fmaf(hr[c], lmW[c * 65 + v], acc);
  lf[idx] = acc;
  out[(size_t)(row0 + r) * 65 + v] = acc;
}

// per-row NLL -> per-block partial (deterministic tree reduce, no atomics)
__global__ __launch_bounds__(256)
void loss_kernel(const float* __restrict__ lf, const int* __restrict__ y,
                 float* __restrict__ partial, int nrows, int row0){
  __shared__ float red[256];
  int r = blockIdx.x * 256 + threadIdx.x;
  float nll = 0.f;
  if (r < nrows){
    const float* L = lf + (size_t)r * 65;
    float mx = -1e30f;
    for (int v = 0; v < 65; ++v) mx = fmaxf(mx, L[v]);
    float sm = 0.f;
    for (int v = 0; v < 65; ++v) sm += expf(L[v] - mx);
    float lse = mx + logf(sm);
    nll = lse - L[y[row0 + r]];
  }
  red[threadIdx.x] = nll;
  __syncthreads();
  for (int st = 128; st; st >>= 1){
    if (threadIdx.x < st) red[threadIdx.x] += red[threadIdx.x + st];
    __syncthreads();
  }
  if (threadIdx.x == 0) partial[blockIdx.x] = red[0];
}

__global__ __launch_bounds__(256)
void loss_red(const float* __restrict__ partial, int n, float* __restrict__ loss_sum){
  __shared__ float red[256];
  float s = 0.f;
  for (int i = threadIdx.x; i < n; i += 256) s += partial[i];
  red[threadIdx.x] = s;
  __syncthreads();
  for (int st = 128; st; st >>= 1){
    if (threadIdx.x < st) red[threadIdx.x] += red[threadIdx.x + st];
    __syncthreads();
  }
  if (threadIdx.x == 0) *loss_sum += red[0];
}

__global__ void loss_fin(const float* __restrict__ loss_sum, float* __restrict__ out){
  if (threadIdx.x == 0)
    out[(size_t)M_TOTAL * 65] = *loss_sum * (1.f / (float)M_TOTAL);
}

extern "C" void kernel_launch(void* const* d_in, const int* in_sizes, int n_in,
                              void* d_out, int out_size, void* d_ws, size_t ws_size,
                              hipStream_t stream) {
  const int*   x    = (const int*)  d_in[0];
  const int*   y    = (const int*)  d_in[1];
  const float* tok  = (const float*)d_in[2];
  const float* pos  = (const float*)d_in[3];
  const float* Wk   = (const float*)d_in[4];
  const float* Wq   = (const float*)d_in[5];
  const float* Wv   = (const float*)d_in[6];
  const float* Wp   = (const float*)d_in[7];
  const float* bp   = (const float*)d_in[8];
  const float* ln1g = (const float*)d_in[9];
  const float* ln1b = (const float*)d_in[10];
  const float* W1   = (const float*)d_in[11];
  const float* b1   = (const float*)d_in[12];
  const float* W2   = (const float*)d_in[13];
  const float* b2   = (const float*)d_in[14];
  const float* ln2g = (const float*)d_in[15];
  const float* ln2b = (const float*)d_in[16];
  const float* lmW  = (const float*)d_in[17];
  const float* lmb  = (const float*)d_in[18];
  float* out = (float*)d_out;

  // ws layout: loss_sum[64] | partial[1024] | bf16 weights | per-row buffers
  float* loss_sum = (float*)d_ws;
  float* partial  = loss_sum + 64;
  unsigned short* WrT = (unsigned short*)(partial + 1024);       // [8][768][256]
  unsigned short* WpT = WrT + (size_t)8 * 768 * 256;             // [8][256][256]
  unsigned short* W1T = WpT + (size_t)8 * 256 * 256;             // [8][1024][256]
  unsigned short* W2T = W1T + (size_t)8 * 1024 * 256;            // [8][256][1024]
  float* bufs = (float*)(W2T + (size_t)8 * 256 * 1024);
  size_t fixed = (size_t)(64 + 1024) * 4 +
                 ((size_t)8 * 768 * 256 + 8 * 256 * 256 + 8 * 1024 * 256 + 8 * 256 * 1024) * 2;
  // per-row: h256 lf65 (f32) + kqv768 h_bf256 attn256 ff1 1024 (bf16)
  const size_t per_row = (size_t)(256 + 65) * 4 + (size_t)(768 + 256 + 256 + 1024) * 2;
  size_t avail = ws_size > fixed ? ws_size - fixed : 0;
  long rmax = (long)(avail / per_row) & ~255L;
  if (rmax < 256) rmax = 256;
  int R = (int)(rmax < (long)M_TOTAL ? rmax : (long)M_TOTAL);

  float* h  = bufs;                                    // [R][256] f32
  float* lf = h + (size_t)R * 256;                     // [R][65]  f32
  unsigned short* kqv_b  = (unsigned short*)(lf + (size_t)R * 65);  // [R][768] bf16
  unsigned short* h_bf   = kqv_b  + (size_t)R * 768;   // [R][256] bf16
  unsigned short* attn_b = h_bf   + (size_t)R * 256;   // [R][256] bf16
  unsigned short* ff1_b  = attn_b + (size_t)R * 256;   // [R][1024] bf16

  zero1<<<1, 64, 0, stream>>>(loss_sum);
  convert_qkv<<<CDIV(8 * 768 * 256, 256), 256, 0, stream>>>(Wk, Wq, Wv, WrT);
  convert_t<<<CDIV(8 * 256 * 256, 256), 256, 0, stream>>>(Wp, WpT, 256, 256, 8 * 256 * 256);
  convert_t<<<CDIV(8 * 1024 * 256, 256), 256, 0, stream>>>(W1, W1T, 1024, 256, 8 * 1024 * 256);
  convert_t<<<CDIV(8 * 256 * 1024, 256), 256, 0, stream>>>(W2, W2T, 256, 1024, 8 * 256 * 1024);

  for (int row0 = 0; row0 < M_TOTAL; row0 += R){
    int nr = (M_TOTAL - row0) < R ? (M_TOTAL - row0) : R;
    int eg = CDIV(nr * 256, 256); if (eg > 8192) eg = 8192;
    embed_kernel<<<eg, 256, 0, stream>>>(x, tok, pos, h, h_bf, row0, nr);
    for (int i = 0; i < 8; ++i){
      gemm_bf<false, true><<<dim3(6, nr / 128), 256, 0, stream>>>(
          h_bf, WrT + (size_t)i * 768 * 256, nullptr, nullptr, kqv_b, 768, 256);
      attn_fused<<<dim3(nr / 32, 4), 128, 0, stream>>>(kqv_b, attn_b);
      gemm_ln<<<nr / 128, 512, 0, stream>>>(
          attn_b, WpT + (size_t)i * 256 * 256, bp + i * 256, h, h_bf,
          ln1g + i * 256, ln1b + i * 256, 256);
      gemm_bf<true, true><<<dim3(8, nr / 128), 256, 0, stream>>>(
          h_bf, W1T + (size_t)i * 1024 * 256, b1 + i * 1024, nullptr, ff1_b, 1024, 256);
      gemm_ln<<<nr / 128, 512, 0, stream>>>(
          ff1_b, W2T + (size_t)i * 256 * 1024, b2 + i * 256, h, h_bf,
          ln2g + i * 256, ln2b + i * 256, 1024);
    }
    logits_kernel<<<CDIV(nr * 65, 256), 256, 0, stream>>>(h, lmW, lmb, lf, out, nr, row0);
    int lb = CDIV(nr, 256);
    loss_kernel<<<lb, 256, 0, stream>>>(lf, y, partial, nr, row0);
    loss_red<<<1, 256, 0, stream>>>(partial, lb, loss_sum);
  }
  loss_fin<<<1, 64, 0, stream>>>(loss_sum, out);
}

// Round 10
// 7764.915 us; speedup vs baseline: 1.2512x; 1.2512x over previous
//
#include <hip/hip_runtime.h>
#include <hip/hip_bf16.h>

#define M_TOTAL 131072
#define ATT_SCALE 0.17677669529663687f
#define LN_EPS 1e-5f
#define CDIV(a,b) (((a)+(b)-1)/(b))

using bf16x8 = __attribute__((ext_vector_type(8))) short;
using f32x4  = __attribute__((ext_vector_type(4))) float;

__device__ __forceinline__ float wredsum(float v){
#pragma unroll
  for (int m = 32; m; m >>= 1) v += __shfl_xor(v, m, 64);
  return v;
}

// fp32 -> bf16 (round-to-nearest-even) as raw bits
__device__ __forceinline__ unsigned short f2b(float x){
  union { float f; unsigned u; } v; v.f = x;
  unsigned r = v.u + 0x7FFFu + ((v.u >> 16) & 1u);
  return (unsigned short)(r >> 16);
}
__device__ __forceinline__ float b2f(unsigned short u){
  union { unsigned u32; float f; } v; v.u32 = (unsigned)u << 16; return v.f;
}

__global__ void zero1(float* p){ if (threadIdx.x == 0) *p = 0.f; }

// ---- one-time weight conversion: fp32 [K][N] -> bf16 transposed [N][K] ----
__global__ void convert_qkv(const float* __restrict__ Wk, const float* __restrict__ Wq,
                            const float* __restrict__ Wv, unsigned short* __restrict__ WrT){
  int idx = blockIdx.x * 256 + threadIdx.x;
  if (idx >= 8 * 768 * 256) return;
  int k = idx & 255;
  int n = (idx >> 8) % 768;
  int i = idx / (768 * 256);
  int sel = n >> 8, nn = n & 255, hh = nn >> 6, d = nn & 63;
  const float* W = sel == 0 ? Wk : sel == 1 ? Wq : Wv;
  WrT[idx] = f2b(W[((size_t)(i * 4 + hh) * 256 + k) * 64 + d]);
}

__global__ void convert_t(const float* __restrict__ in, unsigned short* __restrict__ outp,
                          int N, int K, int total){
  int idx = blockIdx.x * 256 + threadIdx.x;
  if (idx >= total) return;
  int k = idx % K;
  int n = (idx / K) % N;
  int i = idx / (K * N);
  outp[idx] = f2b(in[((size_t)i * K + k) * N + n]);
}

// lmW fp32 [256][65] -> lmWT bf16 [80][256] (rows 65..79 zero) ; lmb -> lmbp[80]
__global__ void convert_lmw(const float* __restrict__ lmW, const float* __restrict__ lmb,
                            unsigned short* __restrict__ lmWT, float* __restrict__ lmbp){
  int idx = blockIdx.x * 256 + threadIdx.x;
  if (idx >= 80 * 256) return;
  int k = idx & 255, c = idx >> 8;
  lmWT[idx] = (c < 65) ? f2b(lmW[k * 65 + c]) : (unsigned short)0;
  if (idx < 80) lmbp[idx] = (idx < 65) ? lmb[idx] : 0.f;
}

// ---- MFMA bf16 GEMM: C[r][n] = A[r][:] @ B[:][n] + bias[n] ----
// A bf16 [M][K]; BT bf16 transposed [N][K]. 128x128 tile, BK=64, 4 waves (2x2).
template<bool RELU, bool BF16OUT>
__global__ __launch_bounds__(256)
void gemm_bf(const unsigned short* __restrict__ A, const unsigned short* __restrict__ BT,
             const float* __restrict__ bias, float* __restrict__ Cf,
             unsigned short* __restrict__ Cb, int N, int K){
  __shared__ unsigned short As[128][72];
  __shared__ unsigned short Bs[128][72];
  const int tid = threadIdx.x;
  const int rowBase = blockIdx.y * 128, colBase = blockIdx.x * 128;
  const int w = tid >> 6, lane = tid & 63;
  const int wm = w >> 1, wn = w & 1;
  const int lm = lane & 15, lk = lane >> 4;
  const int srow = tid >> 3, scol = (tid & 7) * 8;

  f32x4 acc[4][4];
#pragma unroll
  for (int m = 0; m < 4; ++m)
#pragma unroll
    for (int n = 0; n < 4; ++n) acc[m][n] = (f32x4){0.f, 0.f, 0.f, 0.f};

  for (int kt = 0; kt < K; kt += 64){
#pragma unroll
    for (int q = 0; q < 4; ++q){
      int r = srow + 32 * q;
      *(uint4*)&As[r][scol] = *(const uint4*)(A  + (size_t)(rowBase + r) * K + kt + scol);
      *(uint4*)&Bs[r][scol] = *(const uint4*)(BT + (size_t)(colBase + r) * K + kt + scol);
    }
    __syncthreads();
#pragma unroll
    for (int half = 0; half < 2; ++half){
      bf16x8 a[4], b[4];
#pragma unroll
      for (int m = 0; m < 4; ++m)
        a[m] = *(const bf16x8*)&As[wm * 64 + m * 16 + lm][half * 32 + lk * 8];
#pragma unroll
      for (int n = 0; n < 4; ++n)
        b[n] = *(const bf16x8*)&Bs[wn * 64 + n * 16 + lm][half * 32 + lk * 8];
#pragma unroll
      for (int m = 0; m < 4; ++m)
#pragma unroll
        for (int n = 0; n < 4; ++n)
          acc[m][n] = __builtin_amdgcn_mfma_f32_16x16x32_bf16(a[m], b[n], acc[m][n], 0, 0, 0);
    }
    __syncthreads();
  }

#pragma unroll
  for (int m = 0; m < 4; ++m){
#pragma unroll
    for (int n = 0; n < 4; ++n){
      int c = colBase + wn * 64 + n * 16 + lm;
      float bv = bias ? bias[c] : 0.f;
#pragma unroll
      for (int i = 0; i < 4; ++i){
        int r = rowBase + wm * 64 + m * 16 + lk * 4 + i;
        float v = acc[m][n][i] + bv;
        if (RELU) v = fmaxf(v, 0.f);
        if (BF16OUT) Cb[(size_t)r * N + c] = f2b(v);
        else         Cf[(size_t)r * N + c] = v;
      }
    }
  }
}

// h[r][c] = tok[x[m]][c] + pos[x[m]][c] (pos indexed by TOKEN ids -- source bug preserved)
__global__ void embed_kernel(const int* __restrict__ x, const float* __restrict__ tok,
                             const float* __restrict__ pos, float* __restrict__ h,
                             unsigned short* __restrict__ h_bf, int row0, int nrows){
  int total = nrows * 256;
  for (int idx = blockIdx.x * blockDim.x + threadIdx.x; idx < total; idx += gridDim.x * blockDim.x){
    int r = idx >> 8, c = idx & 255;
    int t = x[row0 + r];
    float v = tok[t * 256 + c] + pos[t * 256 + c];
    h[idx] = v;
    h_bf[idx] = f2b(v);
  }
}

// ---- fused attention: one block per (seq, head), 128 threads; kqv in bf16 ----
__global__ __launch_bounds__(128)
void attn_fused(const unsigned short* __restrict__ kqv, unsigned short* __restrict__ attn){
  __shared__ float Kf[32][68];
  __shared__ float Qt[64][33];
  __shared__ float Vf[32][68];
  __shared__ float Ws[32][33];
  const int ls = blockIdx.x, hh = blockIdx.y;
  const int tid = threadIdx.x;

  for (int idx = tid; idx < 512; idx += 128){
    int t = idx >> 4, d4 = idx & 15;
    size_t base = (size_t)(ls * 32 + t) * 768 + hh * 64 + d4 * 4;
    ushort4 k4 = *(const ushort4*)(kqv + base);
    ushort4 q4 = *(const ushort4*)(kqv + base + 256);
    ushort4 v4 = *(const ushort4*)(kqv + base + 512);
    int d = d4 * 4;
    Kf[t][d+0] = b2f(k4.x); Kf[t][d+1] = b2f(k4.y); Kf[t][d+2] = b2f(k4.z); Kf[t][d+3] = b2f(k4.w);
    Qt[d+0][t] = b2f(q4.x); Qt[d+1][t] = b2f(q4.y); Qt[d+2][t] = b2f(q4.z); Qt[d+3][t] = b2f(q4.w);
    Vf[t][d+0] = b2f(v4.x); Vf[t][d+1] = b2f(v4.y); Vf[t][d+2] = b2f(v4.z); Vf[t][d+3] = b2f(v4.w);
  }
  __syncthreads();

  for (int idx = tid; idx < 1024; idx += 128){
    int s = idx & 31, t = idx >> 5;
    if (s <= t){
      float acc = 0.f;
#pragma unroll 16
      for (int d = 0; d < 64; ++d) acc = fmaf(Kf[t][d], Qt[d][s], acc);
      Ws[t][s] = acc * ATT_SCALE;
    }
  }
  __syncthreads();

  if (tid < 32){
    int t = tid;
    float mx = -1e30f;
    for (int s = 0; s <= t; ++s) mx = fmaxf(mx, Ws[t][s]);
    float sm = 0.f;
    for (int s = 0; s <= t; ++s){ float e = expf(Ws[t][s] - mx); Ws[t][s] = e; sm += e; }
    float inv = 1.f / sm;
    for (int s = 0; s <= t; ++s) Ws[t][s] *= inv;
    for (int s = t + 1; s < 32; ++s) Ws[t][s] = 0.f;
  }
  __syncthreads();

  for (int o = tid; o < 512; o += 128){
    int t = o >> 4, d4 = o & 15;
    float4 a4 = {0.f, 0.f, 0.f, 0.f};
#pragma unroll
    for (int s = 0; s < 32; ++s){
      float w = Ws[t][s];
      float4 v = *(const float4*)&Vf[s][d4 * 4];
      a4.x = fmaf(w, v.x, a4.x); a4.y = fmaf(w, v.y, a4.y);
      a4.z = fmaf(w, v.z, a4.z); a4.w = fmaf(w, v.w, a4.w);
    }
    ushort4 o4;
    o4.x = f2b(a4.x); o4.y = f2b(a4.y); o4.z = f2b(a4.z); o4.w = f2b(a4.w);
    *(ushort4*)(attn + (size_t)(ls * 32 + t) * 256 + hh * 64 + d4 * 4) = o4;
  }
}

// h = LayerNorm(h + po) * g + b ; one wave per row, 4 rows per block; emits bf16 copy
__global__ __launch_bounds__(256)
void ln_kernel(float* __restrict__ h, const float* __restrict__ po,
               const float* __restrict__ g, const float* __restrict__ b,
               unsigned short* __restrict__ h_bf){
  const int w = threadIdx.x >> 6, lane = threadIdx.x & 63;
  const size_t r = (size_t)blockIdx.x * 4 + w;
  float v[4];
  float s = 0.f;
#pragma unroll
  for (int j = 0; j < 4; ++j){
    int c = lane + 64 * j;
    v[j] = h[r * 256 + c] + po[r * 256 + c];
    s += v[j];
  }
  s = wredsum(s);
  float mean = s * (1.f / 256.f);
  float q = 0.f;
#pragma unroll
  for (int j = 0; j < 4; ++j){ float d = v[j] - mean; q += d * d; }
  q = wredsum(q);
  float rstd = rsqrtf(q * (1.f / 256.f) + LN_EPS);
#pragma unroll
  for (int j = 0; j < 4; ++j){
    int c = lane + 64 * j;
    float nv = (v[j] - mean) * rstd * g[c] + b[c];
    h[r * 256 + c] = nv;
    h_bf[r * 256 + c] = f2b(nv);
  }
}

// ---- fused logits (MFMA) + log-softmax + NLL ----
// 64 rows/block, 256 threads = 4 waves (16 rows each). lmWT bf16 [80][256], cols padded.
// Writes fp32 logits to out, per-block NLL partial sum to partial[].
__global__ __launch_bounds__(256)
void logits_loss_mfma(const unsigned short* __restrict__ h_bf,
                      const unsigned short* __restrict__ lmWT,
                      const float* __restrict__ lmbp, const int* __restrict__ y,
                      float* __restrict__ out, float* __restrict__ partial,
                      int row0){
  __shared__ unsigned short As[64][136];   // [row][k-tile 128], pad 8
  __shared__ unsigned short Ws[80][136];   // [col][k-tile 128]
  __shared__ float redw[4];
  const int tid = threadIdx.x;
  const int rowBase = blockIdx.x * 64;
  const int w = tid >> 6, lane = tid & 63;
  const int lm = lane & 15, lk = lane >> 4;

  f32x4 acc[5];
#pragma unroll
  for (int n = 0; n < 5; ++n) acc[n] = (f32x4){0.f, 0.f, 0.f, 0.f};

  for (int kt = 0; kt < 256; kt += 128){
    // stage A: 64x128 bf16 = 1024 vec8 loads (4/thread)
#pragma unroll
    for (int q = 0; q < 4; ++q){
      int idx = tid + 256 * q;
      int r = idx >> 4, k8 = (idx & 15) * 8;
      *(uint4*)&As[r][k8] = *(const uint4*)(h_bf + (size_t)(rowBase + r) * 256 + kt + k8);
    }
    // stage W: 80x128 bf16 = 1280 vec8 loads (5/thread)
#pragma unroll
    for (int q = 0; q < 5; ++q){
      int idx = tid + 256 * q;
      int r = idx >> 4, k8 = (idx & 15) * 8;
      *(uint4*)&Ws[r][k8] = *(const uint4*)(lmWT + (size_t)r * 256 + kt + k8);
    }
    __syncthreads();
#pragma unroll
    for (int kc = 0; kc < 4; ++kc){
      bf16x8 a = *(const bf16x8*)&As[w * 16 + lm][kc * 32 + lk * 8];
#pragma unroll
      for (int n = 0; n < 5; ++n){
        bf16x8 bb = *(const bf16x8*)&Ws[n * 16 + lm][kc * 32 + lk * 8];
        acc[n] = __builtin_amdgcn_mfma_f32_16x16x32_bf16(a, bb, acc[n], 0, 0, 0);
      }
    }
    __syncthreads();
  }

  // bias add + fp32 logit writes (cols < 65)
#pragma unroll
  for (int n = 0; n < 5; ++n){
    int c = n * 16 + lm;
    float bv = lmbp[c];
#pragma unroll
    for (int i = 0; i < 4; ++i){
      acc[n][i] += bv;
      if (c < 65){
        int r = rowBase + w * 16 + lk * 4 + i;
        out[(size_t)(row0 + r) * 65 + c] = acc[n][i];
      }
    }
  }

  // per-row log-softmax + NLL (16 lanes share a row; lanes lk*16+lm are contiguous)
  float nll = 0.f;
#pragma unroll
  for (int i = 0; i < 4; ++i){
    float mx = -1e30f;
#pragma unroll
    for (int n = 0; n < 5; ++n)
      if (n * 16 + lm < 65) mx = fmaxf(mx, acc[n][i]);
#pragma unroll
    for (int mask = 1; mask < 16; mask <<= 1) mx = fmaxf(mx, __shfl_xor(mx, mask, 64));
    float se = 0.f;
#pragma unroll
    for (int n = 0; n < 5; ++n)
      if (n * 16 + lm < 65) se += expf(acc[n][i] - mx);
#pragma unroll
    for (int mask = 1; mask < 16; mask <<= 1) se += __shfl_xor(se, mask, 64);
    float lse = mx + logf(se);
    int gr = rowBase + w * 16 + lk * 4 + i;
    int yv = y[row0 + gr];
    float ly = 0.f;
#pragma unroll
    for (int n = 0; n < 5; ++n)
      if (n * 16 + lm == yv) ly = acc[n][i];
#pragma unroll
    for (int mask = 1; mask < 16; mask <<= 1) ly += __shfl_xor(ly, mask, 64);
    nll += lse - ly;
  }
  if (lm != 0) nll = 0.f;
  nll += __shfl_xor(nll, 16, 64);
  nll += __shfl_xor(nll, 32, 64);
  if (lane == 0) redw[w] = nll;
  __syncthreads();
  if (tid == 0) partial[blockIdx.x] = redw[0] + redw[1] + redw[2] + redw[3];
}

__global__ __launch_bounds__(256)
void loss_red(const float* __restrict__ partial, int n, float* __restrict__ loss_sum){
  __shared__ float red[256];
  float s = 0.f;
  for (int i = threadIdx.x; i < n; i += 256) s += partial[i];
  red[threadIdx.x] = s;
  __syncthreads();
  for (int st = 128; st; st >>= 1){
    if (threadIdx.x < st) red[threadIdx.x] += red[threadIdx.x + st];
    __syncthreads();
  }
  if (threadIdx.x == 0) *loss_sum += red[0];
}

__global__ void loss_fin(const float* __restrict__ loss_sum, float* __restrict__ out){
  if (threadIdx.x == 0)
    out[(size_t)M_TOTAL * 65] = *loss_sum * (1.f / (float)M_TOTAL);
}

extern "C" void kernel_launch(void* const* d_in, const int* in_sizes, int n_in,
                              void* d_out, int out_size, void* d_ws, size_t ws_size,
                              hipStream_t stream) {
  const int*   x    = (const int*)  d_in[0];
  const int*   y    = (const int*)  d_in[1];
  const float* tok  = (const float*)d_in[2];
  const float* pos  = (const float*)d_in[3];
  const float* Wk   = (const float*)d_in[4];
  const float* Wq   = (const float*)d_in[5];
  const float* Wv   = (const float*)d_in[6];
  const float* Wp   = (const float*)d_in[7];
  const float* bp   = (const float*)d_in[8];
  const float* ln1g = (const float*)d_in[9];
  const float* ln1b = (const float*)d_in[10];
  const float* W1   = (const float*)d_in[11];
  const float* b1   = (const float*)d_in[12];
  const float* W2   = (const float*)d_in[13];
  const float* b2   = (const float*)d_in[14];
  const float* ln2g = (const float*)d_in[15];
  const float* ln2b = (const float*)d_in[16];
  const float* lmW  = (const float*)d_in[17];
  const float* lmb  = (const float*)d_in[18];
  float* out = (float*)d_out;

  // ws layout: loss_sum[64] | partial[1024] | lmWT+lmbp | bf16 weights | per-row buffers
  float* loss_sum = (float*)d_ws;
  float* partial  = loss_sum + 64;
  unsigned short* lmWT = (unsigned short*)(partial + 1024);      // [80][256]
  float* lmbp = (float*)(lmWT + 80 * 256);                       // [80]
  unsigned short* WrT = (unsigned short*)(lmbp + 80);            // [8][768][256]
  unsigned short* WpT = WrT + (size_t)8 * 768 * 256;             // [8][256][256]
  unsigned short* W1T = WpT + (size_t)8 * 256 * 256;             // [8][1024][256]
  unsigned short* W2T = W1T + (size_t)8 * 1024 * 256;            // [8][256][1024]
  float* bufs = (float*)(W2T + (size_t)8 * 256 * 1024);
  size_t fixed = (size_t)(64 + 1024) * 4 + (size_t)80 * 256 * 2 + 80 * 4 +
                 ((size_t)8 * 768 * 256 + 8 * 256 * 256 + 8 * 1024 * 256 + 8 * 256 * 1024) * 2;
  // per-row: h256 (f32) + kqv768 h_bf256 attn256 ff1 1024 (bf16); po aliases kqv region
  const size_t per_row = (size_t)256 * 4 + (size_t)(768 + 256 + 256 + 1024) * 2;
  size_t avail = ws_size > fixed ? ws_size - fixed : 0;
  long rmax = (long)(avail / per_row) & ~255L;
  if (rmax < 256) rmax = 256;
  int R = (int)(rmax < (long)M_TOTAL ? rmax : (long)M_TOTAL);

  float* h = bufs;                                     // [R][256] f32
  unsigned short* kqv_b  = (unsigned short*)(h + (size_t)R * 256);  // [R][768] bf16
  unsigned short* h_bf   = kqv_b  + (size_t)R * 768;   // [R][256] bf16
  unsigned short* attn_b = h_bf   + (size_t)R * 256;   // [R][256] bf16
  unsigned short* ff1_b  = attn_b + (size_t)R * 256;   // [R][1024] bf16
  float* po = (float*)kqv_b;  // alias: kqv dead after attn_fused, po dead before next QKV

  zero1<<<1, 64, 0, stream>>>(loss_sum);
  convert_qkv<<<CDIV(8 * 768 * 256, 256), 256, 0, stream>>>(Wk, Wq, Wv, WrT);
  convert_t<<<CDIV(8 * 256 * 256, 256), 256, 0, stream>>>(Wp, WpT, 256, 256, 8 * 256 * 256);
  convert_t<<<CDIV(8 * 1024 * 256, 256), 256, 0, stream>>>(W1, W1T, 1024, 256, 8 * 1024 * 256);
  convert_t<<<CDIV(8 * 256 * 1024, 256), 256, 0, stream>>>(W2, W2T, 256, 1024, 8 * 256 * 1024);
  convert_lmw<<<80, 256, 0, stream>>>(lmW, lmb, lmWT, lmbp);

  for (int row0 = 0; row0 < M_TOTAL; row0 += R){
    int nr = (M_TOTAL - row0) < R ? (M_TOTAL - row0) : R;
    int eg = CDIV(nr * 256, 256); if (eg > 8192) eg = 8192;
    embed_kernel<<<eg, 256, 0, stream>>>(x, tok, pos, h, h_bf, row0, nr);
    for (int i = 0; i < 8; ++i){
      gemm_bf<false, true><<<dim3(6, nr / 128), 256, 0, stream>>>(
          h_bf, WrT + (size_t)i * 768 * 256, nullptr, nullptr, kqv_b, 768, 256);
      attn_fused<<<dim3(nr / 32, 4), 128, 0, stream>>>(kqv_b, attn_b);
      gemm_bf<false, false><<<dim3(2, nr / 128), 256, 0, stream>>>(
          attn_b, WpT + (size_t)i * 256 * 256, bp + i * 256, po, nullptr, 256, 256);
      ln_kernel<<<nr / 4, 256, 0, stream>>>(h, po, ln1g + i * 256, ln1b + i * 256, h_bf);
      gemm_bf<true, true><<<dim3(8, nr / 128), 256, 0, stream>>>(
          h_bf, W1T + (size_t)i * 1024 * 256, b1 + i * 1024, nullptr, ff1_b, 1024, 256);
      gemm_bf<false, false><<<dim3(2, nr / 128), 256, 0, stream>>>(
          ff1_b, W2T + (size_t)i * 256 * 1024, b2 + i * 256, po, nullptr, 256, 1024);
      ln_kernel<<<nr / 4, 256, 0, stream>>>(h, po, ln2g + i * 256, ln2b + i * 256, h_bf);
    }
    logits_loss_mfma<<<nr / 64, 256, 0, stream>>>(h_bf, lmWT, lmbp, y, out, partial, row0);
    loss_red<<<1, 256, 0, stream>>>(partial, nr / 64, loss_sum);
  }
  loss_fin<<<1, 64, 0, stream>>>(loss_sum, out);
}

// Round 11
// 7050.633 us; speedup vs baseline: 1.3779x; 1.1013x over previous
//
#include <hip/hip_runtime.h>
#include <hip/hip_bf16.h>

#define M_TOTAL 131072
#define ATT_SCALE 0.17677669529663687f
#define LN_EPS 1e-5f
#define CDIV(a,b) (((a)+(b)-1)/(b))

using bf16x8 = __attribute__((ext_vector_type(8))) short;
using f32x4  = __attribute__((ext_vector_type(4))) float;

__device__ __forceinline__ float wredsum(float v){
#pragma unroll
  for (int m = 32; m; m >>= 1) v += __shfl_xor(v, m, 64);
  return v;
}

// fp32 -> bf16 (round-to-nearest-even) as raw bits
__device__ __forceinline__ unsigned short f2b(float x){
  union { float f; unsigned u; } v; v.f = x;
  unsigned r = v.u + 0x7FFFu + ((v.u >> 16) & 1u);
  return (unsigned short)(r >> 16);
}
__device__ __forceinline__ float b2f(unsigned short u){
  union { unsigned u32; float f; } v; v.u32 = (unsigned)u << 16; return v.f;
}

__global__ void zero1(float* p){ if (threadIdx.x == 0) *p = 0.f; }

// ---- one-time weight conversion: fp32 [K][N] -> bf16 transposed [N][K] ----
__global__ void convert_qkv(const float* __restrict__ Wk, const float* __restrict__ Wq,
                            const float* __restrict__ Wv, unsigned short* __restrict__ WrT){
  int idx = blockIdx.x * 256 + threadIdx.x;
  if (idx >= 8 * 768 * 256) return;
  int k = idx & 255;
  int n = (idx >> 8) % 768;
  int i = idx / (768 * 256);
  int sel = n >> 8, nn = n & 255, hh = nn >> 6, d = nn & 63;
  const float* W = sel == 0 ? Wk : sel == 1 ? Wq : Wv;
  WrT[idx] = f2b(W[((size_t)(i * 4 + hh) * 256 + k) * 64 + d]);
}

__global__ void convert_t(const float* __restrict__ in, unsigned short* __restrict__ outp,
                          int N, int K, int total){
  int idx = blockIdx.x * 256 + threadIdx.x;
  if (idx >= total) return;
  int k = idx % K;
  int n = (idx / K) % N;
  int i = idx / (K * N);
  outp[idx] = f2b(in[((size_t)i * K + k) * N + n]);
}

// lmW fp32 [256][65] -> lmWT bf16 [80][256] (rows 65..79 zero) ; lmb -> lmbp[80]
__global__ void convert_lmw(const float* __restrict__ lmW, const float* __restrict__ lmb,
                            unsigned short* __restrict__ lmWT, float* __restrict__ lmbp){
  int idx = blockIdx.x * 256 + threadIdx.x;
  if (idx >= 80 * 256) return;
  int k = idx & 255, c = idx >> 8;
  lmWT[idx] = (c < 65) ? f2b(lmW[k * 65 + c]) : (unsigned short)0;
  if (idx < 80) lmbp[idx] = (idx < 65) ? lmb[idx] : 0.f;
}

// ---- MFMA bf16 GEMM (m97 structure): C = A @ BT^T + bias, bf16 out ----
// 128x128 tile, BK=64, 4 waves (2x2). global_load_lds width-16 staging into
// XOR-swizzled LDS (linear dest + inverse-swizzled global source + swizzled read).
template<bool RELU>
__global__ __launch_bounds__(256)
void gemm_bf(const unsigned short* __restrict__ A, const unsigned short* __restrict__ BT,
             const float* __restrict__ bias, unsigned short* __restrict__ Cb,
             int N, int K){
  __shared__ unsigned short As[128][64];   // linear rows; data column-swizzled per row
  __shared__ unsigned short Bs[128][64];
  const int tid = threadIdx.x;
  const int rowBase = blockIdx.y * 128, colBase = blockIdx.x * 128;
  const int w = tid >> 6, lane = tid & 63;
  const int wm = w >> 1, wn = w & 1;
  const int lm = lane & 15, lk = lane >> 4;

  // staging geometry: wave w stages rows [w*32, w*32+32), 8 rows per issue (q=0..3).
  // lane -> row = w*32 + q*8 + (lane>>3); LDS write lands at linear lane*16.
  // data for LDS[row][colbyte] comes from global [row][colbyte ^ ((row&7)<<4)],
  // row&7 == lane>>3 for all q (8-row-aligned groups).
  const int sgrow = w * 32 + (lane >> 3);
  const int sgcol = ((((lane & 7) * 16) ^ ((lane >> 3) << 4)) >> 1);   // element offset
  const unsigned short* gA = A  + (size_t)(rowBase + sgrow) * K + sgcol;
  const unsigned short* gB = BT + (size_t)(colBase + sgrow) * K + sgcol;

  f32x4 acc[4][4];
#pragma unroll
  for (int m = 0; m < 4; ++m)
#pragma unroll
    for (int n = 0; n < 4; ++n) acc[m][n] = (f32x4){0.f, 0.f, 0.f, 0.f};

  for (int kt = 0; kt < K; kt += 64){
#pragma unroll
    for (int q = 0; q < 4; ++q){
      __builtin_amdgcn_global_load_lds(
        (const __attribute__((address_space(1))) void*)(gA + (size_t)(q * 8) * K + kt),
        (__attribute__((address_space(3))) void*)&As[w * 32 + q * 8][0], 16, 0, 0);
      __builtin_amdgcn_global_load_lds(
        (const __attribute__((address_space(1))) void*)(gB + (size_t)(q * 8) * K + kt),
        (__attribute__((address_space(3))) void*)&Bs[w * 32 + q * 8][0], 16, 0, 0);
    }
    __syncthreads();   // compiler drains vmcnt(0) before barrier -> LDS data ready
#pragma unroll
    for (int half = 0; half < 2; ++half){
      const int cb = (half * 64 + lk * 16) ^ ((lm & 7) << 4);   // swizzled byte col
      bf16x8 a[4], b[4];
#pragma unroll
      for (int m = 0; m < 4; ++m)
        a[m] = *(const bf16x8*)((const char*)&As[wm * 64 + m * 16 + lm][0] + cb);
#pragma unroll
      for (int n = 0; n < 4; ++n)
        b[n] = *(const bf16x8*)((const char*)&Bs[wn * 64 + n * 16 + lm][0] + cb);
#pragma unroll
      for (int m = 0; m < 4; ++m)
#pragma unroll
        for (int n = 0; n < 4; ++n)
          acc[m][n] = __builtin_amdgcn_mfma_f32_16x16x32_bf16(a[m], b[n], acc[m][n], 0, 0, 0);
    }
    __syncthreads();   // all waves done reading before next-tile overwrite
  }

#pragma unroll
  for (int m = 0; m < 4; ++m){
#pragma unroll
    for (int n = 0; n < 4; ++n){
      int c = colBase + wn * 64 + n * 16 + lm;
      float bv = bias ? bias[c] : 0.f;
#pragma unroll
      for (int i = 0; i < 4; ++i){
        int r = rowBase + wm * 64 + m * 16 + lk * 4 + i;
        float v = acc[m][n][i] + bv;
        if (RELU) v = fmaxf(v, 0.f);
        Cb[(size_t)r * N + c] = f2b(v);
      }
    }
  }
}

// h[r][c] = tok[x[m]][c] + pos[x[m]][c] (pos indexed by TOKEN ids -- source bug preserved)
__global__ void embed_kernel(const int* __restrict__ x, const float* __restrict__ tok,
                             const float* __restrict__ pos, float* __restrict__ h,
                             unsigned short* __restrict__ h_bf, int row0, int nrows){
  int total = nrows * 256;
  for (int idx = blockIdx.x * blockDim.x + threadIdx.x; idx < total; idx += gridDim.x * blockDim.x){
    int r = idx >> 8, c = idx & 255;
    int t = x[row0 + r];
    float v = tok[t * 256 + c] + pos[t * 256 + c];
    h[idx] = v;
    h_bf[idx] = f2b(v);
  }
}

// ---- fused attention: one block per (seq, head), 128 threads; kqv in bf16 ----
__global__ __launch_bounds__(128)
void attn_fused(const unsigned short* __restrict__ kqv, unsigned short* __restrict__ attn){
  __shared__ float Kf[32][68];
  __shared__ float Qt[64][33];
  __shared__ float Vf[32][68];
  __shared__ float Ws[32][33];
  const int ls = blockIdx.x, hh = blockIdx.y;
  const int tid = threadIdx.x;

  for (int idx = tid; idx < 512; idx += 128){
    int t = idx >> 4, d4 = idx & 15;
    size_t base = (size_t)(ls * 32 + t) * 768 + hh * 64 + d4 * 4;
    ushort4 k4 = *(const ushort4*)(kqv + base);
    ushort4 q4 = *(const ushort4*)(kqv + base + 256);
    ushort4 v4 = *(const ushort4*)(kqv + base + 512);
    int d = d4 * 4;
    Kf[t][d+0] = b2f(k4.x); Kf[t][d+1] = b2f(k4.y); Kf[t][d+2] = b2f(k4.z); Kf[t][d+3] = b2f(k4.w);
    Qt[d+0][t] = b2f(q4.x); Qt[d+1][t] = b2f(q4.y); Qt[d+2][t] = b2f(q4.z); Qt[d+3][t] = b2f(q4.w);
    Vf[t][d+0] = b2f(v4.x); Vf[t][d+1] = b2f(v4.y); Vf[t][d+2] = b2f(v4.z); Vf[t][d+3] = b2f(v4.w);
  }
  __syncthreads();

  for (int idx = tid; idx < 1024; idx += 128){
    int s = idx & 31, t = idx >> 5;
    if (s <= t){
      float acc = 0.f;
#pragma unroll 16
      for (int d = 0; d < 64; ++d) acc = fmaf(Kf[t][d], Qt[d][s], acc);
      Ws[t][s] = acc * ATT_SCALE;
    }
  }
  __syncthreads();

  if (tid < 32){
    int t = tid;
    float mx = -1e30f;
    for (int s = 0; s <= t; ++s) mx = fmaxf(mx, Ws[t][s]);
    float sm = 0.f;
    for (int s = 0; s <= t; ++s){ float e = expf(Ws[t][s] - mx); Ws[t][s] = e; sm += e; }
    float inv = 1.f / sm;
    for (int s = 0; s <= t; ++s) Ws[t][s] *= inv;
    for (int s = t + 1; s < 32; ++s) Ws[t][s] = 0.f;
  }
  __syncthreads();

  for (int o = tid; o < 512; o += 128){
    int t = o >> 4, d4 = o & 15;
    float4 a4 = {0.f, 0.f, 0.f, 0.f};
#pragma unroll
    for (int s = 0; s < 32; ++s){
      float w = Ws[t][s];
      float4 v = *(const float4*)&Vf[s][d4 * 4];
      a4.x = fmaf(w, v.x, a4.x); a4.y = fmaf(w, v.y, a4.y);
      a4.z = fmaf(w, v.z, a4.z); a4.w = fmaf(w, v.w, a4.w);
    }
    ushort4 o4;
    o4.x = f2b(a4.x); o4.y = f2b(a4.y); o4.z = f2b(a4.z); o4.w = f2b(a4.w);
    *(ushort4*)(attn + (size_t)(ls * 32 + t) * 256 + hh * 64 + d4 * 4) = o4;
  }
}

// h = LayerNorm(h + po) * g + b ; po is bf16; one wave per row, 4 rows per block
__global__ __launch_bounds__(256)
void ln_kernel(float* __restrict__ h, const unsigned short* __restrict__ po,
               const float* __restrict__ g, const float* __restrict__ b,
               unsigned short* __restrict__ h_bf){
  const int w = threadIdx.x >> 6, lane = threadIdx.x & 63;
  const size_t r = (size_t)blockIdx.x * 4 + w;
  float v[4];
  float s = 0.f;
#pragma unroll
  for (int j = 0; j < 4; ++j){
    int c = lane + 64 * j;
    v[j] = h[r * 256 + c] + b2f(po[r * 256 + c]);
    s += v[j];
  }
  s = wredsum(s);
  float mean = s * (1.f / 256.f);
  float q = 0.f;
#pragma unroll
  for (int j = 0; j < 4; ++j){ float d = v[j] - mean; q += d * d; }
  q = wredsum(q);
  float rstd = rsqrtf(q * (1.f / 256.f) + LN_EPS);
#pragma unroll
  for (int j = 0; j < 4; ++j){
    int c = lane + 64 * j;
    float nv = (v[j] - mean) * rstd * g[c] + b[c];
    h[r * 256 + c] = nv;
    h_bf[r * 256 + c] = f2b(nv);
  }
}

// ---- fused logits (MFMA) + log-softmax + NLL ----
__global__ __launch_bounds__(256)
void logits_loss_mfma(const unsigned short* __restrict__ h_bf,
                      const unsigned short* __restrict__ lmWT,
                      const float* __restrict__ lmbp, const int* __restrict__ y,
                      float* __restrict__ out, float* __restrict__ partial,
                      int row0){
  __shared__ unsigned short As[64][136];
  __shared__ unsigned short Ws[80][136];
  __shared__ float redw[4];
  const int tid = threadIdx.x;
  const int rowBase = blockIdx.x * 64;
  const int w = tid >> 6, lane = tid & 63;
  const int lm = lane & 15, lk = lane >> 4;

  f32x4 acc[5];
#pragma unroll
  for (int n = 0; n < 5; ++n) acc[n] = (f32x4){0.f, 0.f, 0.f, 0.f};

  for (int kt = 0; kt < 256; kt += 128){
#pragma unroll
    for (int q = 0; q < 4; ++q){
      int idx = tid + 256 * q;
      int r = idx >> 4, k8 = (idx & 15) * 8;
      *(uint4*)&As[r][k8] = *(const uint4*)(h_bf + (size_t)(rowBase + r) * 256 + kt + k8);
    }
#pragma unroll
    for (int q = 0; q < 5; ++q){
      int idx = tid + 256 * q;
      int r = idx >> 4, k8 = (idx & 15) * 8;
      *(uint4*)&Ws[r][k8] = *(const uint4*)(lmWT + (size_t)r * 256 + kt + k8);
    }
    __syncthreads();
#pragma unroll
    for (int kc = 0; kc < 4; ++kc){
      bf16x8 a = *(const bf16x8*)&As[w * 16 + lm][kc * 32 + lk * 8];
#pragma unroll
      for (int n = 0; n < 5; ++n){
        bf16x8 bb = *(const bf16x8*)&Ws[n * 16 + lm][kc * 32 + lk * 8];
        acc[n] = __builtin_amdgcn_mfma_f32_16x16x32_bf16(a, bb, acc[n], 0, 0, 0);
      }
    }
    __syncthreads();
  }

#pragma unroll
  for (int n = 0; n < 5; ++n){
    int c = n * 16 + lm;
    float bv = lmbp[c];
#pragma unroll
    for (int i = 0; i < 4; ++i){
      acc[n][i] += bv;
      if (c < 65){
        int r = rowBase + w * 16 + lk * 4 + i;
        out[(size_t)(row0 + r) * 65 + c] = acc[n][i];
      }
    }
  }

  float nll = 0.f;
#pragma unroll
  for (int i = 0; i < 4; ++i){
    float mx = -1e30f;
#pragma unroll
    for (int n = 0; n < 5; ++n)
      if (n * 16 + lm < 65) mx = fmaxf(mx, acc[n][i]);
#pragma unroll
    for (int mask = 1; mask < 16; mask <<= 1) mx = fmaxf(mx, __shfl_xor(mx, mask, 64));
    float se = 0.f;
#pragma unroll
    for (int n = 0; n < 5; ++n)
      if (n * 16 + lm < 65) se += expf(acc[n][i] - mx);
#pragma unroll
    for (int mask = 1; mask < 16; mask <<= 1) se += __shfl_xor(se, mask, 64);
    float lse = mx + logf(se);
    int gr = rowBase + w * 16 + lk * 4 + i;
    int yv = y[row0 + gr];
    float ly = 0.f;
#pragma unroll
    for (int n = 0; n < 5; ++n)
      if (n * 16 + lm == yv) ly = acc[n][i];
#pragma unroll
    for (int mask = 1; mask < 16; mask <<= 1) ly += __shfl_xor(ly, mask, 64);
    nll += lse - ly;
  }
  if (lm != 0) nll = 0.f;
  nll += __shfl_xor(nll, 16, 64);
  nll += __shfl_xor(nll, 32, 64);
  if (lane == 0) redw[w] = nll;
  __syncthreads();
  if (tid == 0) partial[blockIdx.x] = redw[0] + redw[1] + redw[2] + redw[3];
}

__global__ __launch_bounds__(256)
void loss_red(const float* __restrict__ partial, int n, float* __restrict__ loss_sum){
  __shared__ float red[256];
  float s = 0.f;
  for (int i = threadIdx.x; i < n; i += 256) s += partial[i];
  red[threadIdx.x] = s;
  __syncthreads();
  for (int st = 128; st; st >>= 1){
    if (threadIdx.x < st) red[threadIdx.x] += red[threadIdx.x + st];
    __syncthreads();
  }
  if (threadIdx.x == 0) *loss_sum += red[0];
}

__global__ void loss_fin(const float* __restrict__ loss_sum, float* __restrict__ out){
  if (threadIdx.x == 0)
    out[(size_t)M_TOTAL * 65] = *loss_sum * (1.f / (float)M_TOTAL);
}

extern "C" void kernel_launch(void* const* d_in, const int* in_sizes, int n_in,
                              void* d_out, int out_size, void* d_ws, size_t ws_size,
                              hipStream_t stream) {
  const int*   x    = (const int*)  d_in[0];
  const int*   y    = (const int*)  d_in[1];
  const float* tok  = (const float*)d_in[2];
  const float* pos  = (const float*)d_in[3];
  const float* Wk   = (const float*)d_in[4];
  const float* Wq   = (const float*)d_in[5];
  const float* Wv   = (const float*)d_in[6];
  const float* Wp   = (const float*)d_in[7];
  const float* bp   = (const float*)d_in[8];
  const float* ln1g = (const float*)d_in[9];
  const float* ln1b = (const float*)d_in[10];
  const float* W1   = (const float*)d_in[11];
  const float* b1   = (const float*)d_in[12];
  const float* W2   = (const float*)d_in[13];
  const float* b2   = (const float*)d_in[14];
  const float* ln2g = (const float*)d_in[15];
  const float* ln2b = (const float*)d_in[16];
  const float* lmW  = (const float*)d_in[17];
  const float* lmb  = (const float*)d_in[18];
  float* out = (float*)d_out;

  // ws layout: loss_sum[64] | partial[1024] | lmWT+lmbp | bf16 weights | per-row buffers
  float* loss_sum = (float*)d_ws;
  float* partial  = loss_sum + 64;
  unsigned short* lmWT = (unsigned short*)(partial + 1024);      // [80][256]
  float* lmbp = (float*)(lmWT + 80 * 256);                       // [80]
  unsigned short* WrT = (unsigned short*)(lmbp + 80);            // [8][768][256]
  unsigned short* WpT = WrT + (size_t)8 * 768 * 256;             // [8][256][256]
  unsigned short* W1T = WpT + (size_t)8 * 256 * 256;             // [8][1024][256]
  unsigned short* W2T = W1T + (size_t)8 * 1024 * 256;            // [8][256][1024]
  float* bufs = (float*)(W2T + (size_t)8 * 256 * 1024);
  size_t fixed = (size_t)(64 + 1024) * 4 + (size_t)80 * 256 * 2 + 80 * 4 +
                 ((size_t)8 * 768 * 256 + 8 * 256 * 256 + 8 * 1024 * 256 + 8 * 256 * 1024) * 2;
  // per-row: h256 (f32) + kqv768 h_bf256 attn256 ff1 1024 (bf16); po_b aliases kqv region
  const size_t per_row = (size_t)256 * 4 + (size_t)(768 + 256 + 256 + 1024) * 2;
  size_t avail = ws_size > fixed ? ws_size - fixed : 0;
  long rmax = (long)(avail / per_row) & ~255L;
  if (rmax < 256) rmax = 256;
  int R = (int)(rmax < (long)M_TOTAL ? rmax : (long)M_TOTAL);

  float* h = bufs;                                     // [R][256] f32
  unsigned short* kqv_b  = (unsigned short*)(h + (size_t)R * 256);  // [R][768] bf16
  unsigned short* h_bf   = kqv_b  + (size_t)R * 768;   // [R][256] bf16
  unsigned short* attn_b = h_bf   + (size_t)R * 256;   // [R][256] bf16
  unsigned short* ff1_b  = attn_b + (size_t)R * 256;   // [R][1024] bf16
  unsigned short* po_b = kqv_b;  // alias: kqv dead after attn_fused, po dead before next QKV

  zero1<<<1, 64, 0, stream>>>(loss_sum);
  convert_qkv<<<CDIV(8 * 768 * 256, 256), 256, 0, stream>>>(Wk, Wq, Wv, WrT);
  convert_t<<<CDIV(8 * 256 * 256, 256), 256, 0, stream>>>(Wp, WpT, 256, 256, 8 * 256 * 256);
  convert_t<<<CDIV(8 * 1024 * 256, 256), 256, 0, stream>>>(W1, W1T, 1024, 256, 8 * 1024 * 256);
  convert_t<<<CDIV(8 * 256 * 1024, 256), 256, 0, stream>>>(W2, W2T, 256, 1024, 8 * 256 * 1024);
  convert_lmw<<<80, 256, 0, stream>>>(lmW, lmb, lmWT, lmbp);

  for (int row0 = 0; row0 < M_TOTAL; row0 += R){
    int nr = (M_TOTAL - row0) < R ? (M_TOTAL - row0) : R;
    int eg = CDIV(nr * 256, 256); if (eg > 8192) eg = 8192;
    embed_kernel<<<eg, 256, 0, stream>>>(x, tok, pos, h, h_bf, row0, nr);
    for (int i = 0; i < 8; ++i){
      gemm_bf<false><<<dim3(6, nr / 128), 256, 0, stream>>>(
          h_bf, WrT + (size_t)i * 768 * 256, nullptr, kqv_b, 768, 256);
      attn_fused<<<dim3(nr / 32, 4), 128, 0, stream>>>(kqv_b, attn_b);
      gemm_bf<false><<<dim3(2, nr / 128), 256, 0, stream>>>(
          attn_b, WpT + (size_t)i * 256 * 256, bp + i * 256, po_b, 256, 256);
      ln_kernel<<<nr / 4, 256, 0, stream>>>(h, po_b, ln1g + i * 256, ln1b + i * 256, h_bf);
      gemm_bf<true><<<dim3(8, nr / 128), 256, 0, stream>>>(
          h_bf, W1T + (size_t)i * 1024 * 256, b1 + i * 1024, ff1_b, 1024, 256);
      gemm_bf<false><<<dim3(2, nr / 128), 256, 0, stream>>>(
          ff1_b, W2T + (size_t)i * 256 * 1024, b2 + i * 256, po_b, 256, 1024);
      ln_kernel<<<nr / 4, 256, 0, stream>>>(h, po_b, ln2g + i * 256, ln2b + i * 256, h_bf);
    }
    logits_loss_mfma<<<nr / 64, 256, 0, stream>>>(h_bf, lmWT, lmbp, y, out, partial, row0);
    loss_red<<<1, 256, 0, stream>>>(partial, nr / 64, loss_sum);
  }
  loss_fin<<<1, 64, 0, stream>>>(loss_sum, out);
}

// Round 12
// 5816.701 us; speedup vs baseline: 1.6702x; 1.2121x over previous
//
#include <hip/hip_runtime.h>
#include <hip/hip_bf16.h>

#define M_TOTAL 131072
#define ATT_SCALE 0.17677669529663687f
#define LN_EPS 1e-5f
#define CDIV(a,b) (((a)+(b)-1)/(b))

using bf16x8 = __attribute__((ext_vector_type(8))) short;
using f32x4  = __attribute__((ext_vector_type(4))) float;

__device__ __forceinline__ float wredsum(float v){
#pragma unroll
  for (int m = 32; m; m >>= 1) v += __shfl_xor(v, m, 64);
  return v;
}

// fp32 -> bf16 (round-to-nearest-even) as raw bits
__device__ __forceinline__ unsigned short f2b(float x){
  union { float f; unsigned u; } v; v.f = x;
  unsigned r = v.u + 0x7FFFu + ((v.u >> 16) & 1u);
  return (unsigned short)(r >> 16);
}
__device__ __forceinline__ float b2f(unsigned short u){
  union { unsigned u32; float f; } v; v.u32 = (unsigned)u << 16; return v.f;
}

__global__ void zero1(float* p){ if (threadIdx.x == 0) *p = 0.f; }

// ---- one-time weight conversion: fp32 [K][N] -> bf16 transposed [N][K] ----
__global__ void convert_qkv(const float* __restrict__ Wk, const float* __restrict__ Wq,
                            const float* __restrict__ Wv, unsigned short* __restrict__ WrT){
  int idx = blockIdx.x * 256 + threadIdx.x;
  if (idx >= 8 * 768 * 256) return;
  int k = idx & 255;
  int n = (idx >> 8) % 768;
  int i = idx / (768 * 256);
  int sel = n >> 8, nn = n & 255, hh = nn >> 6, d = nn & 63;
  const float* W = sel == 0 ? Wk : sel == 1 ? Wq : Wv;
  WrT[idx] = f2b(W[((size_t)(i * 4 + hh) * 256 + k) * 64 + d]);
}

__global__ void convert_t(const float* __restrict__ in, unsigned short* __restrict__ outp,
                          int N, int K, int total){
  int idx = blockIdx.x * 256 + threadIdx.x;
  if (idx >= total) return;
  int k = idx % K;
  int n = (idx / K) % N;
  int i = idx / (K * N);
  outp[idx] = f2b(in[((size_t)i * K + k) * N + n]);
}

// lmW fp32 [256][65] -> lmWT bf16 [80][256] (rows 65..79 zero) ; lmb -> lmbp[80]
__global__ void convert_lmw(const float* __restrict__ lmW, const float* __restrict__ lmb,
                            unsigned short* __restrict__ lmWT, float* __restrict__ lmbp){
  int idx = blockIdx.x * 256 + threadIdx.x;
  if (idx >= 80 * 256) return;
  int k = idx & 255, c = idx >> 8;
  lmWT[idx] = (c < 65) ? f2b(lmW[k * 65 + c]) : (unsigned short)0;
  if (idx < 80) lmbp[idx] = (idx < 65) ? lmb[idx] : 0.f;
}

// ---- MFMA bf16 GEMM (m97 structure): C = A @ BT^T + bias, bf16 out ----
template<bool RELU>
__global__ __launch_bounds__(256)
void gemm_bf(const unsigned short* __restrict__ A, const unsigned short* __restrict__ BT,
             const float* __restrict__ bias, unsigned short* __restrict__ Cb,
             int N, int K){
  __shared__ unsigned short As[128][64];
  __shared__ unsigned short Bs[128][64];
  const int tid = threadIdx.x;
  const int rowBase = blockIdx.y * 128, colBase = blockIdx.x * 128;
  const int w = tid >> 6, lane = tid & 63;
  const int wm = w >> 1, wn = w & 1;
  const int lm = lane & 15, lk = lane >> 4;

  const int sgrow = w * 32 + (lane >> 3);
  const int sgcol = ((((lane & 7) * 16) ^ ((lane >> 3) << 4)) >> 1);
  const unsigned short* gA = A  + (size_t)(rowBase + sgrow) * K + sgcol;
  const unsigned short* gB = BT + (size_t)(colBase + sgrow) * K + sgcol;

  f32x4 acc[4][4];
#pragma unroll
  for (int m = 0; m < 4; ++m)
#pragma unroll
    for (int n = 0; n < 4; ++n) acc[m][n] = (f32x4){0.f, 0.f, 0.f, 0.f};

  for (int kt = 0; kt < K; kt += 64){
#pragma unroll
    for (int q = 0; q < 4; ++q){
      __builtin_amdgcn_global_load_lds(
        (const __attribute__((address_space(1))) void*)(gA + (size_t)(q * 8) * K + kt),
        (__attribute__((address_space(3))) void*)&As[w * 32 + q * 8][0], 16, 0, 0);
      __builtin_amdgcn_global_load_lds(
        (const __attribute__((address_space(1))) void*)(gB + (size_t)(q * 8) * K + kt),
        (__attribute__((address_space(3))) void*)&Bs[w * 32 + q * 8][0], 16, 0, 0);
    }
    __syncthreads();
#pragma unroll
    for (int half = 0; half < 2; ++half){
      const int cb = (half * 64 + lk * 16) ^ ((lm & 7) << 4);
      bf16x8 a[4], b[4];
#pragma unroll
      for (int m = 0; m < 4; ++m)
        a[m] = *(const bf16x8*)((const char*)&As[wm * 64 + m * 16 + lm][0] + cb);
#pragma unroll
      for (int n = 0; n < 4; ++n)
        b[n] = *(const bf16x8*)((const char*)&Bs[wn * 64 + n * 16 + lm][0] + cb);
#pragma unroll
      for (int m = 0; m < 4; ++m)
#pragma unroll
        for (int n = 0; n < 4; ++n)
          acc[m][n] = __builtin_amdgcn_mfma_f32_16x16x32_bf16(a[m], b[n], acc[m][n], 0, 0, 0);
    }
    __syncthreads();
  }

#pragma unroll
  for (int m = 0; m < 4; ++m){
#pragma unroll
    for (int n = 0; n < 4; ++n){
      int c = colBase + wn * 64 + n * 16 + lm;
      float bv = bias ? bias[c] : 0.f;
#pragma unroll
      for (int i = 0; i < 4; ++i){
        int r = rowBase + wm * 64 + m * 16 + lk * 4 + i;
        float v = acc[m][n][i] + bv;
        if (RELU) v = fmaxf(v, 0.f);
        Cb[(size_t)r * N + c] = f2b(v);
      }
    }
  }
}

// h[r][c] = tok[x[m]][c] + pos[x[m]][c] (pos indexed by TOKEN ids -- source bug preserved)
__global__ void embed_kernel(const int* __restrict__ x, const float* __restrict__ tok,
                             const float* __restrict__ pos, float* __restrict__ h,
                             unsigned short* __restrict__ h_bf, int row0, int nrows){
  int total = nrows * 256;
  for (int idx = blockIdx.x * blockDim.x + threadIdx.x; idx < total; idx += gridDim.x * blockDim.x){
    int r = idx >> 8, c = idx & 255;
    int t = x[row0 + r];
    float v = tok[t * 256 + c] + pos[t * 256 + c];
    h[idx] = v;
    h_bf[idx] = f2b(v);
  }
}

// ---- MFMA fused attention: one block per sequence, 4 waves = 4 heads ----
// scores = K @ Q^T * SCALE (source semantics), causal softmax in-register,
// P -> bf16 via LDS layout shuffle, PV via MFMA with V transposed in LDS.
__global__ __launch_bounds__(256)
void attn_mfma(const unsigned short* __restrict__ kqv, unsigned short* __restrict__ attn){
  __shared__ __align__(16) unsigned short VT[4][64 * 40];  // [head][d][s] stride 40
  __shared__ __align__(16) unsigned short PH[4][32 * 40];  // [head][t][s] stride 40
  const int ls = blockIdx.x;
  const int tid = threadIdx.x;
  const int hd = tid >> 6, lane = tid & 63;
  const int lm = lane & 15, lk = lane >> 4;

  // ---- stage V transposed: 32 rows x 256 cols (V section), 1024 ushort8 loads ----
#pragma unroll
  for (int it = 0; it < 4; ++it){
    int idx = it * 256 + tid;        // row fastest -> conflict-free VT writes
    int row = idx & 31, col = (idx >> 5) * 8;
    int hh = col >> 6, d = col & 63;
    union { uint4 v4; unsigned short s[8]; } u;
    u.v4 = *(const uint4*)(kqv + (size_t)(ls * 32 + row) * 768 + 512 + col);
#pragma unroll
    for (int j = 0; j < 8; ++j)
      VT[hh][(d + j) * 40 + row] = u.s[j];
  }
  __syncthreads();

  // ---- scores: S = K @ Q^T, fragments gathered directly from global (L2-hot) ----
  const unsigned short* Kg = kqv + (size_t)(ls * 32) * 768 + hd * 64;
  const unsigned short* Qg = Kg + 256;
  f32x4 sacc[2][2];
#pragma unroll
  for (int m = 0; m < 2; ++m)
#pragma unroll
    for (int n = 0; n < 2; ++n) sacc[m][n] = (f32x4){0.f, 0.f, 0.f, 0.f};
#pragma unroll
  for (int kk = 0; kk < 2; ++kk){
    bf16x8 a[2], b[2];
#pragma unroll
    for (int m = 0; m < 2; ++m)
      a[m] = *(const bf16x8*)(Kg + (size_t)(m * 16 + lm) * 768 + kk * 32 + lk * 8);
#pragma unroll
    for (int n = 0; n < 2; ++n)
      b[n] = *(const bf16x8*)(Qg + (size_t)(n * 16 + lm) * 768 + kk * 32 + lk * 8);
#pragma unroll
    for (int m = 0; m < 2; ++m)
#pragma unroll
      for (int n = 0; n < 2; ++n)
        sacc[m][n] = __builtin_amdgcn_mfma_f32_16x16x32_bf16(a[m], b[n], sacc[m][n], 0, 0, 0);
  }

  // ---- causal softmax in-register; C/D layout: row = m*16+lk*4+i, col = n*16+lm ----
#pragma unroll
  for (int m = 0; m < 2; ++m){
#pragma unroll
    for (int i = 0; i < 4; ++i){
      int t = m * 16 + lk * 4 + i;
      float v0 = sacc[m][0][i] * ATT_SCALE;
      float v1 = sacc[m][1][i] * ATT_SCALE;
      bool m0 = (lm <= t), m1 = (16 + lm <= t);
      float mx = fmaxf(m0 ? v0 : -1e30f, m1 ? v1 : -1e30f);
#pragma unroll
      for (int msk = 1; msk < 16; msk <<= 1) mx = fmaxf(mx, __shfl_xor(mx, msk, 64));
      float e0 = m0 ? expf(v0 - mx) : 0.f;
      float e1 = m1 ? expf(v1 - mx) : 0.f;
      float sm = e0 + e1;
#pragma unroll
      for (int msk = 1; msk < 16; msk <<= 1) sm += __shfl_xor(sm, msk, 64);
      float inv = 1.f / sm;
      PH[hd][t * 40 + lm]      = f2b(e0 * inv);
      PH[hd][t * 40 + 16 + lm] = f2b(e1 * inv);
    }
  }
  __syncthreads();

  // ---- PV: O = P @ VT^T (K=32, one MFMA per fragment) ----
  f32x4 pacc[2][4];
  {
    bf16x8 a[2], b[4];
#pragma unroll
    for (int m = 0; m < 2; ++m)
      a[m] = *(const bf16x8*)&PH[hd][(m * 16 + lm) * 40 + lk * 8];
#pragma unroll
    for (int n = 0; n < 4; ++n)
      b[n] = *(const bf16x8*)&VT[hd][(n * 16 + lm) * 40 + lk * 8];
#pragma unroll
    for (int m = 0; m < 2; ++m)
#pragma unroll
      for (int n = 0; n < 4; ++n)
        pacc[m][n] = __builtin_amdgcn_mfma_f32_16x16x32_bf16(
            a[m], b[n], (f32x4){0.f, 0.f, 0.f, 0.f}, 0, 0, 0);
  }

  // ---- write attn (bf16): row = m*16+lk*4+i, col d = n*16+lm ----
#pragma unroll
  for (int m = 0; m < 2; ++m)
#pragma unroll
    for (int i = 0; i < 4; ++i){
      int t = m * 16 + lk * 4 + i;
      size_t base = (size_t)(ls * 32 + t) * 256 + hd * 64;
#pragma unroll
      for (int n = 0; n < 4; ++n)
        attn[base + n * 16 + lm] = f2b(pacc[m][n][i]);
    }
}

// h = LayerNorm(h + po) * g + b ; po is bf16; one wave per row, 4 rows per block
__global__ __launch_bounds__(256)
void ln_kernel(float* __restrict__ h, const unsigned short* __restrict__ po,
               const float* __restrict__ g, const float* __restrict__ b,
               unsigned short* __restrict__ h_bf){
  const int w = threadIdx.x >> 6, lane = threadIdx.x & 63;
  const size_t r = (size_t)blockIdx.x * 4 + w;
  float v[4];
  float s = 0.f;
#pragma unroll
  for (int j = 0; j < 4; ++j){
    int c = lane + 64 * j;
    v[j] = h[r * 256 + c] + b2f(po[r * 256 + c]);
    s += v[j];
  }
  s = wredsum(s);
  float mean = s * (1.f / 256.f);
  float q = 0.f;
#pragma unroll
  for (int j = 0; j < 4; ++j){ float d = v[j] - mean; q += d * d; }
  q = wredsum(q);
  float rstd = rsqrtf(q * (1.f / 256.f) + LN_EPS);
#pragma unroll
  for (int j = 0; j < 4; ++j){
    int c = lane + 64 * j;
    float nv = (v[j] - mean) * rstd * g[c] + b[c];
    h[r * 256 + c] = nv;
    h_bf[r * 256 + c] = f2b(nv);
  }
}

// ---- fused logits (MFMA) + log-softmax + NLL ----
__global__ __launch_bounds__(256)
void logits_loss_mfma(const unsigned short* __restrict__ h_bf,
                      const unsigned short* __restrict__ lmWT,
                      const float* __restrict__ lmbp, const int* __restrict__ y,
                      float* __restrict__ out, float* __restrict__ partial,
                      int row0){
  __shared__ unsigned short As[64][136];
  __shared__ unsigned short Ws[80][136];
  __shared__ float redw[4];
  const int tid = threadIdx.x;
  const int rowBase = blockIdx.x * 64;
  const int w = tid >> 6, lane = tid & 63;
  const int lm = lane & 15, lk = lane >> 4;

  f32x4 acc[5];
#pragma unroll
  for (int n = 0; n < 5; ++n) acc[n] = (f32x4){0.f, 0.f, 0.f, 0.f};

  for (int kt = 0; kt < 256; kt += 128){
#pragma unroll
    for (int q = 0; q < 4; ++q){
      int idx = tid + 256 * q;
      int r = idx >> 4, k8 = (idx & 15) * 8;
      *(uint4*)&As[r][k8] = *(const uint4*)(h_bf + (size_t)(rowBase + r) * 256 + kt + k8);
    }
#pragma unroll
    for (int q = 0; q < 5; ++q){
      int idx = tid + 256 * q;
      int r = idx >> 4, k8 = (idx & 15) * 8;
      *(uint4*)&Ws[r][k8] = *(const uint4*)(lmWT + (size_t)r * 256 + kt + k8);
    }
    __syncthreads();
#pragma unroll
    for (int kc = 0; kc < 4; ++kc){
      bf16x8 a = *(const bf16x8*)&As[w * 16 + lm][kc * 32 + lk * 8];
#pragma unroll
      for (int n = 0; n < 5; ++n){
        bf16x8 bb = *(const bf16x8*)&Ws[n * 16 + lm][kc * 32 + lk * 8];
        acc[n] = __builtin_amdgcn_mfma_f32_16x16x32_bf16(a, bb, acc[n], 0, 0, 0);
      }
    }
    __syncthreads();
  }

#pragma unroll
  for (int n = 0; n < 5; ++n){
    int c = n * 16 + lm;
    float bv = lmbp[c];
#pragma unroll
    for (int i = 0; i < 4; ++i){
      acc[n][i] += bv;
      if (c < 65){
        int r = rowBase + w * 16 + lk * 4 + i;
        out[(size_t)(row0 + r) * 65 + c] = acc[n][i];
      }
    }
  }

  float nll = 0.f;
#pragma unroll
  for (int i = 0; i < 4; ++i){
    float mx = -1e30f;
#pragma unroll
    for (int n = 0; n < 5; ++n)
      if (n * 16 + lm < 65) mx = fmaxf(mx, acc[n][i]);
#pragma unroll
    for (int mask = 1; mask < 16; mask <<= 1) mx = fmaxf(mx, __shfl_xor(mx, mask, 64));
    float se = 0.f;
#pragma unroll
    for (int n = 0; n < 5; ++n)
      if (n * 16 + lm < 65) se += expf(acc[n][i] - mx);
#pragma unroll
    for (int mask = 1; mask < 16; mask <<= 1) se += __shfl_xor(se, mask, 64);
    float lse = mx + logf(se);
    int gr = rowBase + w * 16 + lk * 4 + i;
    int yv = y[row0 + gr];
    float ly = 0.f;
#pragma unroll
    for (int n = 0; n < 5; ++n)
      if (n * 16 + lm == yv) ly = acc[n][i];
#pragma unroll
    for (int mask = 1; mask < 16; mask <<= 1) ly += __shfl_xor(ly, mask, 64);
    nll += lse - ly;
  }
  if (lm != 0) nll = 0.f;
  nll += __shfl_xor(nll, 16, 64);
  nll += __shfl_xor(nll, 32, 64);
  if (lane == 0) redw[w] = nll;
  __syncthreads();
  if (tid == 0) partial[blockIdx.x] = redw[0] + redw[1] + redw[2] + redw[3];
}

__global__ __launch_bounds__(256)
void loss_red(const float* __restrict__ partial, int n, float* __restrict__ loss_sum){
  __shared__ float red[256];
  float s = 0.f;
  for (int i = threadIdx.x; i < n; i += 256) s += partial[i];
  red[threadIdx.x] = s;
  __syncthreads();
  for (int st = 128; st; st >>= 1){
    if (threadIdx.x < st) red[threadIdx.x] += red[threadIdx.x + st];
    __syncthreads();
  }
  if (threadIdx.x == 0) *loss_sum += red[0];
}

__global__ void loss_fin(const float* __restrict__ loss_sum, float* __restrict__ out){
  if (threadIdx.x == 0)
    out[(size_t)M_TOTAL * 65] = *loss_sum * (1.f / (float)M_TOTAL);
}

extern "C" void kernel_launch(void* const* d_in, const int* in_sizes, int n_in,
                              void* d_out, int out_size, void* d_ws, size_t ws_size,
                              hipStream_t stream) {
  const int*   x    = (const int*)  d_in[0];
  const int*   y    = (const int*)  d_in[1];
  const float* tok  = (const float*)d_in[2];
  const float* pos  = (const float*)d_in[3];
  const float* Wk   = (const float*)d_in[4];
  const float* Wq   = (const float*)d_in[5];
  const float* Wv   = (const float*)d_in[6];
  const float* Wp   = (const float*)d_in[7];
  const float* bp   = (const float*)d_in[8];
  const float* ln1g = (const float*)d_in[9];
  const float* ln1b = (const float*)d_in[10];
  const float* W1   = (const float*)d_in[11];
  const float* b1   = (const float*)d_in[12];
  const float* W2   = (const float*)d_in[13];
  const float* b2   = (const float*)d_in[14];
  const float* ln2g = (const float*)d_in[15];
  const float* ln2b = (const float*)d_in[16];
  const float* lmW  = (const float*)d_in[17];
  const float* lmb  = (const float*)d_in[18];
  float* out = (float*)d_out;

  // ws layout: loss_sum[64] | partial[1024] | lmWT+lmbp | bf16 weights | per-row buffers
  float* loss_sum = (float*)d_ws;
  float* partial  = loss_sum + 64;
  unsigned short* lmWT = (unsigned short*)(partial + 1024);      // [80][256]
  float* lmbp = (float*)(lmWT + 80 * 256);                       // [80]
  unsigned short* WrT = (unsigned short*)(lmbp + 80);            // [8][768][256]
  unsigned short* WpT = WrT + (size_t)8 * 768 * 256;             // [8][256][256]
  unsigned short* W1T = WpT + (size_t)8 * 256 * 256;             // [8][1024][256]
  unsigned short* W2T = W1T + (size_t)8 * 1024 * 256;            // [8][256][1024]
  float* bufs = (float*)(W2T + (size_t)8 * 256 * 1024);
  size_t fixed = (size_t)(64 + 1024) * 4 + (size_t)80 * 256 * 2 + 80 * 4 +
                 ((size_t)8 * 768 * 256 + 8 * 256 * 256 + 8 * 1024 * 256 + 8 * 256 * 1024) * 2;
  const size_t per_row = (size_t)256 * 4 + (size_t)(768 + 256 + 256 + 1024) * 2;
  size_t avail = ws_size > fixed ? ws_size - fixed : 0;
  long rmax = (long)(avail / per_row) & ~255L;
  if (rmax < 256) rmax = 256;
  int R = (int)(rmax < (long)M_TOTAL ? rmax : (long)M_TOTAL);

  float* h = bufs;                                     // [R][256] f32
  unsigned short* kqv_b  = (unsigned short*)(h + (size_t)R * 256);  // [R][768] bf16
  unsigned short* h_bf   = kqv_b  + (size_t)R * 768;   // [R][256] bf16
  unsigned short* attn_b = h_bf   + (size_t)R * 256;   // [R][256] bf16
  unsigned short* ff1_b  = attn_b + (size_t)R * 256;   // [R][1024] bf16
  unsigned short* po_b = kqv_b;  // alias: kqv dead after attn, po dead before next QKV

  zero1<<<1, 64, 0, stream>>>(loss_sum);
  convert_qkv<<<CDIV(8 * 768 * 256, 256), 256, 0, stream>>>(Wk, Wq, Wv, WrT);
  convert_t<<<CDIV(8 * 256 * 256, 256), 256, 0, stream>>>(Wp, WpT, 256, 256, 8 * 256 * 256);
  convert_t<<<CDIV(8 * 1024 * 256, 256), 256, 0, stream>>>(W1, W1T, 1024, 256, 8 * 1024 * 256);
  convert_t<<<CDIV(8 * 256 * 1024, 256), 256, 0, stream>>>(W2, W2T, 256, 1024, 8 * 256 * 1024);
  convert_lmw<<<80, 256, 0, stream>>>(lmW, lmb, lmWT, lmbp);

  for (int row0 = 0; row0 < M_TOTAL; row0 += R){
    int nr = (M_TOTAL - row0) < R ? (M_TOTAL - row0) : R;
    int eg = CDIV(nr * 256, 256); if (eg > 8192) eg = 8192;
    embed_kernel<<<eg, 256, 0, stream>>>(x, tok, pos, h, h_bf, row0, nr);
    for (int i = 0; i < 8; ++i){
      gemm_bf<false><<<dim3(6, nr / 128), 256, 0, stream>>>(
          h_bf, WrT + (size_t)i * 768 * 256, nullptr, kqv_b, 768, 256);
      attn_mfma<<<nr / 32, 256, 0, stream>>>(kqv_b, attn_b);
      gemm_bf<false><<<dim3(2, nr / 128), 256, 0, stream>>>(
          attn_b, WpT + (size_t)i * 256 * 256, bp + i * 256, po_b, 256, 256);
      ln_kernel<<<nr / 4, 256, 0, stream>>>(h, po_b, ln1g + i * 256, ln1b + i * 256, h_bf);
      gemm_bf<true><<<dim3(8, nr / 128), 256, 0, stream>>>(
          h_bf, W1T + (size_t)i * 1024 * 256, b1 + i * 1024, ff1_b, 1024, 256);
      gemm_bf<false><<<dim3(2, nr / 128), 256, 0, stream>>>(
          ff1_b, W2T + (size_t)i * 256 * 1024, b2 + i * 256, po_b, 256, 1024);
      ln_kernel<<<nr / 4, 256, 0, stream>>>(h, po_b, ln2g + i * 256, ln2b + i * 256, h_bf);
    }
    logits_loss_mfma<<<nr / 64, 256, 0, stream>>>(h_bf, lmWT, lmbp, y, out, partial, row0);
    loss_red<<<1, 256, 0, stream>>>(partial, nr / 64, loss_sum);
  }
  loss_fin<<<1, 64, 0, stream>>>(loss_sum, out);
}